// Round 6
// baseline (162.686 us; speedup 1.0000x reference)
//
#include <hip/hip_runtime.h>
#include <stdint.h>

typedef unsigned short u16;
typedef unsigned int u32;
typedef __attribute__((ext_vector_type(8))) short bf16x8;
typedef __attribute__((ext_vector_type(4))) float f32x4;

#define NTOK 1024      // H*W
#define DMODEL 256
#define NHEAD 8
#define DK 32
#define NBATCH 8
#define PER_B (DMODEL * NTOK)   // 262144

__device__ __forceinline__ float b2f(u16 h) {
    union { unsigned u; float f; } c; c.u = ((unsigned)h) << 16; return c.f;
}
__device__ __forceinline__ u16 f2b(float f) {
    unsigned u = __float_as_uint(f);
    unsigned r = u + 0x7fffu + ((u >> 16) & 1u);
    return (u16)(r >> 16);
}

// ---------------- Kernel 1: fused weight-convert + LN partial sums ----------------
__global__ void prep(const float* __restrict__ Wq, const float* __restrict__ Wk,
                     const float* __restrict__ Wv, const float* __restrict__ Wo,
                     u16* __restrict__ wb,
                     const float* __restrict__ x, float* __restrict__ part) {
    int bx = blockIdx.x;
    int t = threadIdx.x;
    if (bx < 256) {
        int m = bx >> 6;
        const float* W = (m == 0) ? Wq : (m == 1) ? Wk : (m == 2) ? Wv : Wo;
        int i = ((bx & 63) * 256 + t) * 4;
        float4 v = *(const float4*)&W[i];
        ushort4 o;
        o.x = f2b(v.x); o.y = f2b(v.y); o.z = f2b(v.z); o.w = f2b(v.w);
        *(ushort4*)&wb[m * 65536 + i] = o;
        return;
    }
    int blk = bx - 256;
    int b = blk >> 3, sl = blk & 7;
    int w = t >> 6, l = t & 63;
    const float* xb = x + (size_t)b * PER_B + sl * (PER_B / 8);
    float s = 0.f, ss = 0.f;
    for (int base = 0; base < PER_B / 8; base += 1024) {
        float4 v = *(const float4*)&xb[base + t * 4];
        s += v.x + v.y + v.z + v.w;
        ss += v.x * v.x + v.y * v.y + v.z * v.z + v.w * v.w;
    }
    for (int d = 1; d < 64; d <<= 1) {
        s += __shfl_xor(s, d, 64);
        ss += __shfl_xor(ss, d, 64);
    }
    __shared__ float red[2][4];
    if (l == 0) { red[0][w] = s; red[1][w] = ss; }
    __syncthreads();
    if (t == 0) {
        float S = red[0][0] + red[0][1] + red[0][2] + red[0][3];
        float SS = red[1][0] + red[1][1] + red[1][2] + red[1][3];
        part[(b * 8 + sl) * 2] = S;
        part[(b * 8 + sl) * 2 + 1] = SS;
    }
}

// ---------------- Kernel 2: normalize + transpose [c,n] -> [n,c], fp32 -> bf16 ----------------
__global__ void normT(const float* __restrict__ x, const float* __restrict__ part,
                      u16* __restrict__ xn) {
    int b = blockIdx.z;
    int n0 = blockIdx.x * 32;
    int c0 = blockIdx.y * 32;
    int tx = threadIdx.x, ty = threadIdx.y;   // (32, 8)
    __shared__ float s_mu, s_rs;
    __shared__ float tile[32][33];
    if (tx == 0 && ty == 0) {
        float S = 0.f, SS = 0.f;
        for (int i = 0; i < 8; ++i) { S += part[(b * 8 + i) * 2]; SS += part[(b * 8 + i) * 2 + 1]; }
        float mu = S / (float)PER_B;
        float var = SS / (float)PER_B - mu * mu;
        s_mu = mu;
        s_rs = rsqrtf(var + 1e-5f);
    }
    __syncthreads();
    float mu = s_mu, rs = s_rs;
    const float* xb = x + (size_t)b * PER_B;
#pragma unroll
    for (int i = 0; i < 4; ++i) {
        int c = c0 + ty + i * 8;
        tile[ty + i * 8][tx] = (xb[c * NTOK + n0 + tx] - mu) * rs;
    }
    __syncthreads();
    u16* xnb = xn + (size_t)b * PER_B;
#pragma unroll
    for (int i = 0; i < 4; ++i) {
        int n = n0 + ty + i * 8;
        xnb[n * DMODEL + c0 + tx] = f2b(tile[tx][ty + i * 8]);
    }
}

// ---------------- Kernel 3: QKV projection GEMM (LDS-staged) ----------------
// grid (16 m-tiles, 12 o-tiles, 8 b); q-scale folds DK^-0.5 * log2(e) for attn's exp2 path.
__global__ __launch_bounds__(256) void qkv_gemm(
    const u16* __restrict__ xn, const u16* __restrict__ wb,
    const float* __restrict__ bq, const float* __restrict__ bk,
    const float* __restrict__ bv,
    u16* __restrict__ qo, u16* __restrict__ ko, u16* __restrict__ vo) {
    int mt = blockIdx.x;
    int ot = blockIdx.y;
    int b = blockIdx.z;
    int sel = ot >> 2;            // 0=q 1=k 2=v
    int o0 = (ot & 3) * 64;
    const u16* W = wb + sel * 65536;
    const float* bias = (sel == 0) ? bq : (sel == 1) ? bk : bv;

    __shared__ u16 As[64][40];
    __shared__ u16 Bs[64][40];
    int t = threadIdx.x;
    int w = t >> 6, l = t & 63;
    int lr = t >> 2;
    int lc = (t & 3) * 8;
    int qd = l >> 4, ln = l & 15;

    const u16* xb = xn + ((size_t)b * NTOK + mt * 64) * DMODEL;
    f32x4 acc[4] = {};
    for (int kb = 0; kb < 8; ++kb) {
        *(uint4*)&As[lr][lc] = *(const uint4*)&xb[lr * DMODEL + kb * 32 + lc];
        *(uint4*)&Bs[lr][lc] = *(const uint4*)&W[(o0 + lr) * DMODEL + kb * 32 + lc];
        __syncthreads();
        bf16x8 af = *(const bf16x8*)&As[w * 16 + ln][qd * 8];
#pragma unroll
        for (int ns = 0; ns < 4; ++ns) {
            bf16x8 bf = *(const bf16x8*)&Bs[ns * 16 + ln][qd * 8];
            acc[ns] = __builtin_amdgcn_mfma_f32_16x16x32_bf16(af, bf, acc[ns], 0, 0, 0);
        }
        __syncthreads();
    }
    if (sel < 2) {
        u16* outp = (sel == 0) ? qo : ko;
        // q: DK^-0.5 * log2(e) so attn uses exp2 directly
        float scale = (sel == 0) ? 0.25505654344884634f : 1.0f;
#pragma unroll
        for (int ns = 0; ns < 4; ++ns) {
            int o = o0 + ns * 16 + ln;
            float bias_f = bias[o];
            int head = o >> 5, d = o & 31;
#pragma unroll
            for (int r = 0; r < 4; ++r) {
                int n_row = mt * 64 + w * 16 + qd * 4 + r;
                float v = (acc[ns][r] + bias_f) * scale;
                outp[(((size_t)b * NHEAD + head) * NTOK + n_row) * DK + d] = f2b(v);
            }
        }
    } else {
        // V transposed: vo[bh][dv][n]
        int n0 = mt * 64 + w * 16 + qd * 4;
#pragma unroll
        for (int ns = 0; ns < 4; ++ns) {
            int o = o0 + ns * 16 + ln;
            float bias_f = bias[o];
            int head = o >> 5, d = o & 31;
            ushort4 pk;
            pk.x = f2b(acc[ns][0] + bias_f);
            pk.y = f2b(acc[ns][1] + bias_f);
            pk.z = f2b(acc[ns][2] + bias_f);
            pk.w = f2b(acc[ns][3] + bias_f);
            *(ushort4*)&vo[(((size_t)b * NHEAD + head) * DK + d) * NTOK + n0] = pk;
        }
    }
}

// ---------------- Kernel 4: attention — LDS-staged K/V, double-buffered ----------------
// grid (64 bh, 16 qp): bh fastest -> XCD L2 affinity. Block: 64 q x 1024 keys, 4 waves (16 q each).
// Per chunk of 128 keys: cooperative bulk uint4 staging of K[128][32] and Vt[32][128] into LDS
// (double-buffered, loads issued a full chunk ahead -> latency hidden), then all-wave compute:
// S^T = mfma(kf, qf) -> exp2 -> packed b64 P (per-wave LDS, in-order DS, no barrier) -> PV.
// One __syncthreads per chunk. LDS rows padded (36 / 134) for <=2-way (free) bank aliasing.
__global__ __launch_bounds__(256) void attn(
    const u16* __restrict__ qws, const u16* __restrict__ kws,
    const u16* __restrict__ vtws, u16* __restrict__ tmp) {
    int bh = blockIdx.x;
    int qp = blockIdx.y;
    int b = bh >> 3, h = bh & 7;
    const u16* Q  = qws  + (size_t)bh * NTOK * DK;
    const u16* K  = kws  + (size_t)bh * NTOK * DK;
    const u16* Vt = vtws + (size_t)bh * DK * NTOK;   // [dv][n]

    __shared__ u16 Ks[2][128][36];    // 18.0 KB
    __shared__ u16 Vts[2][32][134];   // 16.75 KB
    __shared__ u16 Ps[4][16][134];    // 16.75 KB (per-wave P tiles)

    int t = threadIdx.x;
    int w = t >> 6, l = t & 63;
    int qd = l >> 4, ln = l & 15;
    u16* psw = &Ps[w][0][0];

    // Q fragment (B operand of S^T): q-col = ln, k = qd*8..+7
    bf16x8 qf = *(const bf16x8*)&Q[(qp * 64 + w * 16 + ln) * DK + qd * 8];

    // staging indices (per thread, 2 uint4 each for K and Vt per chunk)
    int krow0 = t >> 2, kch0 = (t & 3) * 8;            // idx = t
    int krow1 = (t + 256) >> 2, kch1 = kch0;           // idx = t+256 (same ch bits)
    int vrow0 = t >> 4, vch0 = (t & 15) * 8;
    int vrow1 = (t + 256) >> 4, vch1 = vch0;

    // P addresses (loop-invariant)
    int wadr[8];
#pragma unroll
    for (int ns = 0; ns < 8; ++ns)
        wadr[ns] = ln * 134 + ns * 16 + qd * 4;        // b64: keys ns*16+qd*4..+3 at q-row ln
    const bf16x8* rdp[4];
#pragma unroll
    for (int ks = 0; ks < 4; ++ks)
        rdp[ks] = (const bf16x8*)&psw[ln * 134 + ks * 32 + qd * 8];

    float lsum = 0.f;
    f32x4 oacc[2] = {};

    // prologue: load + stage chunk 0
    uint4 kreg0 = *(const uint4*)&K[(0 * 128 + krow0) * DK + kch0];
    uint4 kreg1 = *(const uint4*)&K[(0 * 128 + krow1) * DK + kch1];
    uint4 vreg0 = *(const uint4*)&Vt[vrow0 * NTOK + 0 * 128 + vch0];
    uint4 vreg1 = *(const uint4*)&Vt[vrow1 * NTOK + 0 * 128 + vch1];
    *(uint4*)&Ks[0][krow0][kch0] = kreg0;
    *(uint4*)&Ks[0][krow1][kch1] = kreg1;
    *(uint4*)&Vts[0][vrow0][vch0] = vreg0;
    *(uint4*)&Vts[0][vrow1][vch1] = vreg1;
    __syncthreads();

    for (int c = 0; c < 8; ++c) {
        int buf = c & 1;
        if (c < 7) {
            int k0 = (c + 1) * 128;
            kreg0 = *(const uint4*)&K[(k0 + krow0) * DK + kch0];
            kreg1 = *(const uint4*)&K[(k0 + krow1) * DK + kch1];
            vreg0 = *(const uint4*)&Vt[vrow0 * NTOK + k0 + vch0];
            vreg1 = *(const uint4*)&Vt[vrow1 * NTOK + k0 + vch1];
        }

        // S^T = K Q^T over 128 keys (8 tiles of 16); exp2; packed b64 P writes
#pragma unroll
        for (int ns = 0; ns < 8; ++ns) {
            bf16x8 kf = *(const bf16x8*)&Ks[buf][ns * 16 + ln][qd * 8];
            f32x4 z = {0.f, 0.f, 0.f, 0.f};
            f32x4 s = __builtin_amdgcn_mfma_f32_16x16x32_bf16(kf, qf, z, 0, 0, 0);
            float p0 = __builtin_amdgcn_exp2f(s[0]);
            float p1 = __builtin_amdgcn_exp2f(s[1]);
            float p2 = __builtin_amdgcn_exp2f(s[2]);
            float p3 = __builtin_amdgcn_exp2f(s[3]);
            lsum += (p0 + p1) + (p2 + p3);
            u32 dw0 = __builtin_amdgcn_perm(__float_as_uint(p1), __float_as_uint(p0), 0x07060302u);
            u32 dw1 = __builtin_amdgcn_perm(__float_as_uint(p3), __float_as_uint(p2), 0x07060302u);
            *(uint2*)&psw[wadr[ns]] = make_uint2(dw0, dw1);
        }

        // O += P V over the 128 keys (4 k-steps of 32)
#pragma unroll
        for (int ks = 0; ks < 4; ++ks) {
            bf16x8 pf = *rdp[ks];
            bf16x8 vf0 = *(const bf16x8*)&Vts[buf][ 0 + ln][ks * 32 + qd * 8];
            bf16x8 vf1 = *(const bf16x8*)&Vts[buf][16 + ln][ks * 32 + qd * 8];
            oacc[0] = __builtin_amdgcn_mfma_f32_16x16x32_bf16(pf, vf0, oacc[0], 0, 0, 0);
            oacc[1] = __builtin_amdgcn_mfma_f32_16x16x32_bf16(pf, vf1, oacc[1], 0, 0, 0);
        }

        if (c < 7) {
            int nbuf = buf ^ 1;
            *(uint4*)&Ks[nbuf][krow0][kch0] = kreg0;
            *(uint4*)&Ks[nbuf][krow1][kch1] = kreg1;
            *(uint4*)&Vts[nbuf][vrow0][vch0] = vreg0;
            *(uint4*)&Vts[nbuf][vrow1][vch1] = vreg1;
            __syncthreads();
        }
    }

    // l: keys are distributed across qd groups -> reduce over qd (lanes ln, ln+16, ln+32, ln+48)
    lsum += __shfl_xor(lsum, 16, 64);
    lsum += __shfl_xor(lsum, 32, 64);

    // linv for the 4 q-rows this lane's C-registers cover: q = qd*4 + r (l held at lane q)
    float linv[4];
#pragma unroll
    for (int r = 0; r < 4; ++r)
        linv[r] = 1.0f / __shfl(lsum, qd * 4 + r, 64);

    // epilogue: tmp[b][n][h*32 + dv]
#pragma unroll
    for (int ns = 0; ns < 2; ++ns) {
#pragma unroll
        for (int r = 0; r < 4; ++r) {
            int n_row = qp * 64 + w * 16 + qd * 4 + r;
            float v = oacc[ns][r] * linv[r];
            tmp[((size_t)b * NTOK + n_row) * DMODEL + h * DK + ns * 16 + ln] = f2b(v);
        }
    }
}

// ---------------- Kernel 5: output projection + bias + residual (LDS-staged, fp32 out) ----------------
__global__ __launch_bounds__(256) void oproj(
    const u16* __restrict__ tmp, const u16* __restrict__ wb,
    const float* __restrict__ bo, const float* __restrict__ x,
    float* __restrict__ out) {
    int mt = blockIdx.x;
    int ot = blockIdx.y;
    int b = blockIdx.z;
    const u16* Wo = wb + 3 * 65536;

    __shared__ u16 As[64][40];
    __shared__ u16 Bs[64][40];
    int t = threadIdx.x;
    int w = t >> 6, l = t & 63;
    int lr = t >> 2;
    int lc = (t & 3) * 8;
    int qd = l >> 4, ln = l & 15;

    const u16* ab = tmp + ((size_t)b * NTOK + mt * 64) * DMODEL;
    f32x4 acc[4] = {};
    for (int kb = 0; kb < 8; ++kb) {
        *(uint4*)&As[lr][lc] = *(const uint4*)&ab[lr * DMODEL + kb * 32 + lc];
        *(uint4*)&Bs[lr][lc] = *(const uint4*)&Wo[(ot * 64 + lr) * DMODEL + kb * 32 + lc];
        __syncthreads();
        bf16x8 af = *(const bf16x8*)&As[w * 16 + ln][qd * 8];
#pragma unroll
        for (int ns = 0; ns < 4; ++ns) {
            bf16x8 bf = *(const bf16x8*)&Bs[ns * 16 + ln][qd * 8];
            acc[ns] = __builtin_amdgcn_mfma_f32_16x16x32_bf16(af, bf, acc[ns], 0, 0, 0);
        }
        __syncthreads();
    }
    const float* xb = x + (size_t)b * PER_B;
    float* ob = out + (size_t)b * PER_B;
#pragma unroll
    for (int ns = 0; ns < 4; ++ns) {
        int o = ot * 64 + ns * 16 + ln;
        float bias_f = bo[o];
#pragma unroll
        for (int r = 0; r < 4; ++r) {
            int n_row = mt * 64 + w * 16 + qd * 4 + r;
            size_t idx = (size_t)n_row * DMODEL + o;
            ob[idx] = acc[ns][r] + bias_f + xb[idx];
        }
    }
}

extern "C" void kernel_launch(void* const* d_in, const int* in_sizes, int n_in,
                              void* d_out, int out_size, void* d_ws, size_t ws_size,
                              hipStream_t stream) {
    const float* x  = (const float*)d_in[0];
    const float* Wq = (const float*)d_in[1];
    const float* bq = (const float*)d_in[2];
    const float* Wk = (const float*)d_in[3];
    const float* bk = (const float*)d_in[4];
    const float* Wv = (const float*)d_in[5];
    const float* bv = (const float*)d_in[6];
    const float* Wo = (const float*)d_in[7];
    const float* bo = (const float*)d_in[8];
    float* out = (float*)d_out;

    char* ws = (char*)d_ws;
    float* part = (float*)ws;                          // 1 KB
    u16* wb  = (u16*)(ws + 1024);                      // 512 KB
    u16* xn  = (u16*)(ws + 1024 + (512u << 10));       // 4 MB (reused as attn output tmp)
    u16* qws = (u16*)(ws + 1024 + (512u << 10) + (4u << 20));
    u16* kws = (u16*)(ws + 1024 + (512u << 10) + (8u << 20));
    u16* vws = (u16*)(ws + 1024 + (512u << 10) + (12u << 20));  // transposed [bh][dv][n]
    u16* tmp = xn;

    hipLaunchKernelGGL(prep, dim3(320), dim3(256), 0, stream, Wq, Wk, Wv, Wo, wb, x, part);
    hipLaunchKernelGGL(normT, dim3(32, 8, 8), dim3(32, 8), 0, stream, x, part, xn);
    hipLaunchKernelGGL(qkv_gemm, dim3(16, 12, 8), dim3(256), 0, stream,
                       xn, wb, bq, bk, bv, qws, kws, vws);
    hipLaunchKernelGGL(attn, dim3(64, 16), dim3(256), 0, stream, qws, kws, vws, tmp);
    hipLaunchKernelGGL(oproj, dim3(16, 4, 8), dim3(256), 0, stream, tmp, wb, bo, x, out);
}